// Round 5
// baseline (279.814 us; speedup 1.0000x reference)
//
#include <hip/hip_runtime.h>
#include <math.h>

#define BB 8
#define LL 4096
#define HH 512
#define NN 512
#define TT 256        // truncated FIR length
#define NS 128        // tap-pair steps (TT/2)
#define LT 16         // output rows per wave tile

typedef _Float16 half2_t __attribute__((ext_vector_type(2)));
typedef unsigned int u32;

#if __has_builtin(__builtin_amdgcn_fdot2)
__device__ __forceinline__ float fdot2(half2_t a, half2_t b, float c) {
    return __builtin_amdgcn_fdot2(a, b, c, false);
}
#else
__device__ __forceinline__ float fdot2(half2_t a, half2_t b, float c) {
    return c + (float)a.x * (float)b.x + (float)a.y * (float)b.y;
}
#endif

// ---------------------------------------------------------------------------
// Kernel 1 (fused prep), 3 branches by blockIdx:
//   [0, 4096)        : LayerNorm + fp16 pack of adjacent L-row pairs
//   [4096, 4160)     : transpose+pack C [H,N] -> Cpk[N,H] float2(cr,ci)
//   [4160, 4672)     : PQ[n][t] = float2(Re(s_n w_n^t), Im(s_n w_n^t))
#define LN_BLKS (BB * LL / 8)
__global__ __launch_bounds__(256) void prep_kernel(const float* __restrict__ x,
                                                   const float* __restrict__ w,
                                                   const float* __restrict__ bia,
                                                   const float* __restrict__ Cr,
                                                   const float* __restrict__ Ci,
                                                   const float* __restrict__ LR,
                                                   const float* __restrict__ LI,
                                                   u32* __restrict__ u2,
                                                   float2* __restrict__ Cpk,
                                                   float2* __restrict__ PQ) {
    __shared__ float tileR[64][65];
    __shared__ float tileI[64][65];
    if (blockIdx.x >= LN_BLKS + 64) {
        // ---- PQ branch: one n per block, t = tid over 256 ----
        int bi = blockIdx.x - (LN_BLKS + 64);
        int idx = bi * 256 + threadIdx.x;
        int t = idx & 255;
        int n = idx >> 8;
        float lr = -expf(LR[n]);
        float li = expf(LI[n]);
        float el = expf(lr);
        float sn, cs;
        sincosf(li, &sn, &cs);
        float nr = el * cs - 1.0f;
        float ni = el * sn;
        float inv = 1.0f / (lr * lr + li * li);
        float sr = (nr * lr + ni * li) * inv;   // s = (e^lam-1)/lam
        float si = (ni * lr - nr * li) * inv;
        float tf = (float)t;
        float e2 = expf(lr * tf);
        float s2, c2;
        sincosf(li * tf, &s2, &c2);
        float er = e2 * c2, ei = e2 * s2;       // w^t
        PQ[idx] = make_float2(sr * er - si * ei, sr * ei + si * er);
        return;
    }
    if (blockIdx.x >= LN_BLKS) {
        // ---- transpose+pack branch ----
        int tb = blockIdx.x - LN_BLKS;   // 0..63
        int h0 = (tb & 7) * 64;
        int n0 = (tb >> 3) * 64;
        int c = threadIdx.x & 63;
        int r0 = threadIdx.x >> 6;
        #pragma unroll
        for (int i = 0; i < 16; ++i) {
            int r = r0 + i * 4;
            tileR[r][c] = Cr[(size_t)(h0 + r) * NN + n0 + c];
            tileI[r][c] = Ci[(size_t)(h0 + r) * NN + n0 + c];
        }
        __syncthreads();
        #pragma unroll
        for (int i = 0; i < 16; ++i) {
            int r = r0 + i * 4;
            Cpk[(size_t)(n0 + r) * HH + h0 + c] = make_float2(tileR[c][r], tileI[c][r]);
        }
        return;
    }
    // ---- layernorm branch: one wave per L-row pair ----
    int wave = threadIdx.x >> 6;
    int lane = threadIdx.x & 63;
    size_t pair = (size_t)blockIdx.x * 4 + wave;
    const float* xr0 = x + pair * 2 * HH;
    const float* xr1 = xr0 + HH;
    float4 a0 = *(const float4*)(xr0 + lane * 4);
    float4 a1 = *(const float4*)(xr0 + 256 + lane * 4);
    float4 b0 = *(const float4*)(xr1 + lane * 4);
    float4 b1 = *(const float4*)(xr1 + 256 + lane * 4);
    float sA  = a0.x + a0.y + a0.z + a0.w + a1.x + a1.y + a1.z + a1.w;
    float qA  = a0.x*a0.x + a0.y*a0.y + a0.z*a0.z + a0.w*a0.w
              + a1.x*a1.x + a1.y*a1.y + a1.z*a1.z + a1.w*a1.w;
    float sB  = b0.x + b0.y + b0.z + b0.w + b1.x + b1.y + b1.z + b1.w;
    float qB  = b0.x*b0.x + b0.y*b0.y + b0.z*b0.z + b0.w*b0.w
              + b1.x*b1.x + b1.y*b1.y + b1.z*b1.z + b1.w*b1.w;
    #pragma unroll
    for (int off = 1; off < 64; off <<= 1) {
        sA += __shfl_xor(sA, off, 64);
        qA += __shfl_xor(qA, off, 64);
        sB += __shfl_xor(sB, off, 64);
        qB += __shfl_xor(qB, off, 64);
    }
    float mA = sA * (1.0f / 512.0f);
    float rA = rsqrtf(qA * (1.0f / 512.0f) - mA * mA + 1e-5f);
    float mB = sB * (1.0f / 512.0f);
    float rB = rsqrtf(qB * (1.0f / 512.0f) - mB * mB + 1e-5f);
    float4 w0 = *(const float4*)(w + lane * 4);
    float4 w1 = *(const float4*)(w + 256 + lane * 4);
    float4 c0 = *(const float4*)(bia + lane * 4);
    float4 c1 = *(const float4*)(bia + 256 + lane * 4);
    uint4 o0, o1;
    {
        half2_t p;
        p.x = (_Float16)((a0.x - mA) * rA * w0.x + c0.x);
        p.y = (_Float16)((b0.x - mB) * rB * w0.x + c0.x);
        o0.x = __builtin_bit_cast(u32, p);
        p.x = (_Float16)((a0.y - mA) * rA * w0.y + c0.y);
        p.y = (_Float16)((b0.y - mB) * rB * w0.y + c0.y);
        o0.y = __builtin_bit_cast(u32, p);
        p.x = (_Float16)((a0.z - mA) * rA * w0.z + c0.z);
        p.y = (_Float16)((b0.z - mB) * rB * w0.z + c0.z);
        o0.z = __builtin_bit_cast(u32, p);
        p.x = (_Float16)((a0.w - mA) * rA * w0.w + c0.w);
        p.y = (_Float16)((b0.w - mB) * rB * w0.w + c0.w);
        o0.w = __builtin_bit_cast(u32, p);
        p.x = (_Float16)((a1.x - mA) * rA * w1.x + c1.x);
        p.y = (_Float16)((b1.x - mB) * rB * w1.x + c1.x);
        o1.x = __builtin_bit_cast(u32, p);
        p.x = (_Float16)((a1.y - mA) * rA * w1.y + c1.y);
        p.y = (_Float16)((b1.y - mB) * rB * w1.y + c1.y);
        o1.y = __builtin_bit_cast(u32, p);
        p.x = (_Float16)((a1.z - mA) * rA * w1.z + c1.z);
        p.y = (_Float16)((b1.z - mB) * rB * w1.z + c1.z);
        o1.z = __builtin_bit_cast(u32, p);
        p.x = (_Float16)((a1.w - mA) * rA * w1.w + c1.w);
        p.y = (_Float16)((b1.w - mB) * rB * w1.w + c1.w);
        o1.w = __builtin_bit_cast(u32, p);
    }
    *(uint4*)(u2 + pair * HH + lane * 4) = o0;
    *(uint4*)(u2 + pair * HH + 256 + lane * 4) = o1;
}

// ---------------------------------------------------------------------------
// Kernel 2: KT[t][h] = sum_n cr*P[n][t] - ci*Q[n][t].  2 t's per block,
// h-half per block; PQ loads are wave-uniform (scalar), Cpk coalesced float2.
__global__ __launch_bounds__(256) void build_kt(const float2* __restrict__ Cpk,
                                                const float2* __restrict__ PQ,
                                                float* __restrict__ KT) {
    int blk = blockIdx.x;            // 256 blocks
    int t0 = (blk >> 1) * 2;
    int half = blk & 1;
    int h = half * 256 + threadIdx.x;
    float k0 = 0.0f, k1 = 0.0f;
    const float4* pq4 = (const float4*)(PQ + t0);   // row n: PQ[n*256 + t0..t0+1]
    #pragma unroll 8
    for (int n = 0; n < NN; ++n) {
        float2 c = Cpk[(size_t)n * HH + h];
        float4 f = pq4[(size_t)n * 128];            // (P[t0],Q[t0],P[t0+1],Q[t0+1])
        k0 = fmaf(c.x, f.x, k0);
        k0 = fmaf(-c.y, f.y, k0);
        k1 = fmaf(c.x, f.z, k1);
        k1 = fmaf(-c.y, f.w, k1);
    }
    KT[(size_t)t0 * HH + h] = k0;
    KT[(size_t)(t0 + 1) * HH + h] = k1;
}

// ---------------------------------------------------------------------------
// Kernel 3: pack K into step-indexed swapped half2 pairs.
// KQ[s][h].x = (K[255-2s], K[254-2s])  (odd-j pair)
// KQ[s][h].y = (K[256-2s], K[255-2s])  (even-j pair; K[256]=0)
__global__ void pack_k(const float* __restrict__ KT, uint2* __restrict__ KQ) {
    int idx = blockIdx.x * 256 + threadIdx.x;   // 128*512 entries
    int s = idx >> 9;
    int h = idx & 511;
    float k0 = KT[(254 - 2 * s) * HH + h];
    float k1 = KT[(255 - 2 * s) * HH + h];
    float k2 = (s == 0) ? 0.0f : KT[(256 - 2 * s) * HH + h];
    half2_t kx, ky;
    kx.x = (_Float16)k1; kx.y = (_Float16)k0;
    ky.x = (_Float16)k2; ky.y = (_Float16)k1;
    KQ[idx] = make_uint2(__builtin_bit_cast(u32, kx), __builtin_bit_cast(u32, ky));
}

// ---------------------------------------------------------------------------
// Kernel 4: causal FIR conv via v_dot2_f32_f16 + D*u residual.
// Block = 64 h x 4 consecutive l-tiles (wave = tile, lane = h): the 4 waves
// hit the same KQ lines (L1 reuse, 4x less L2 K-traffic) and overlapping u
// windows (~3.5x less u traffic).  K ring = 8 (refill 8 steps ahead),
// u ring = 32 (32 steps ahead).  No upper clamp: u2 padded by 16 rows.

template <bool PRED>
__device__ __forceinline__ u32 load_v(const u32* __restrict__ ub2, int vi) {
    int c = vi;
    if (PRED && c < 0) c = 0;
    u32 val = ub2[(size_t)c * HH];
    if (PRED && vi < 0) val = 0u;
    return val;
}

#define SLOT(p) ((p) < 16 ? W[(p)] : X[(p) - 16])

// KMODE: 1 = load 16 taps (knext+k), 2 = load first 8 only (tail block)
template <bool PRED, bool LOADU, int KMODE>
__device__ __forceinline__ void conv_block(const u32* __restrict__ ub2,
                                           const uint2* __restrict__ kqb,
                                           float (&acc)[LT], u32 (&W)[16], u32 (&X)[16],
                                           uint2 (&KR)[8], int ubase, int knext) {
    #pragma unroll
    for (int k = 0; k < 16; ++k) {
        const bool dok = (KMODE == 1) || (KMODE == 2 && k < 8);
        u32 nv = 0u;
        uint2 kv = make_uint2(0u, 0u);
        if (LOADU) nv = load_v<PRED>(ub2, ubase + k);
        if (dok) kv = kqb[(size_t)(knext + k) * HH];
        uint2 kq = KR[k & 7];
        half2_t kx = __builtin_bit_cast(half2_t, kq.x);
        half2_t ky = __builtin_bit_cast(half2_t, kq.y);
        #pragma unroll
        for (int m = 0; m < 8; ++m) {
            half2_t ve = __builtin_bit_cast(half2_t, SLOT(k + m));
            half2_t vo = __builtin_bit_cast(half2_t, SLOT(k + m + 1));
            acc[2 * m]     = fdot2(ve, ky, acc[2 * m]);
            acc[2 * m + 1] = fdot2(vo, kx, acc[2 * m + 1]);
        }
        if (LOADU) W[k] = nv;
        if (dok) KR[k & 7] = kv;
    }
}

template <bool PRED>
__device__ __forceinline__ void conv_all(const u32* __restrict__ ub2,
                                         const uint2* __restrict__ kqb,
                                         float (&acc)[LT], u32 (&A)[16], u32 (&B)[16],
                                         uint2 (&KR)[8], int Vm1) {
    #pragma unroll
    for (int j = 0; j < 16; ++j) A[j] = load_v<PRED>(ub2, Vm1 + j);
    #pragma unroll
    for (int j = 0; j < 16; ++j) B[j] = load_v<PRED>(ub2, Vm1 + 16 + j);
    #pragma unroll
    for (int q = 0; q < 8; ++q) KR[q] = kqb[(size_t)q * HH];
    #pragma unroll 1
    for (int sbp = 0; sbp < 3; ++sbp) {   // sb = 0..5; knext(sb) = 16*sb+8
        conv_block<PRED, true, 1>(ub2, kqb, acc, A, B, KR,
                                  Vm1 + 32 * sbp + 32, 32 * sbp + 8);
        conv_block<PRED, true, 1>(ub2, kqb, acc, B, A, KR,
                                  Vm1 + 32 * sbp + 48, 32 * sbp + 24);
    }
    // sb = 6: u loads cover v[l0/2..l0/2+15] into A; K loads s=104..119
    conv_block<PRED, true, 1>(ub2, kqb, acc, A, B, KR, Vm1 + 128, 104);
    // sb = 7: K loads s=120..127 at k<8; no u loads; A preserved for epilogue
    conv_block<PRED, false, 2>(ub2, kqb, acc, B, A, KR, 0, 120);
}

__global__ __launch_bounds__(256, 4) void conv_kernel(const u32* __restrict__ u2,
                                                      const uint2* __restrict__ KQ,
                                                      const float* __restrict__ KT,
                                                      const float* __restrict__ Dp,
                                                      float* __restrict__ y) {
    int lane = threadIdx.x & 63;
    int g = threadIdx.x >> 6;            // wave = l-subtile
    int blk = blockIdx.x;
    int hg = blk & 7;                    // 8 h-groups of 64
    int tg = (blk >> 3) & 63;            // 64 tile-groups of 4 tiles
    int b = blk >> 9;                    // 8 batches
    int h = hg * 64 + lane;
    int l0 = (tg * 4 + g) * LT;
    const u32* ub2 = u2 + (size_t)b * (LL / 2) * HH + h;
    const uint2* kqb = KQ + h;
    int Vm1 = l0 / 2 - 128;
    float acc[LT];
    u32 A[16], B[16];
    uint2 KR[8];
    #pragma unroll
    for (int j = 0; j < LT; ++j) acc[j] = 0.0f;
    if (l0 >= TT) {
        conv_all<false>(ub2, kqb, acc, A, B, KR, Vm1);
    } else {
        conv_all<true>(ub2, kqb, acc, A, B, KR, Vm1);
    }
    float dv = Dp[h];
    float k0f = KT[h];          // K[0]
    float ce = k0f + dv;
    float* yb = y + ((size_t)b * LL + l0) * HH + h;
    // A[m] = v[l0/2+m] = (u[l0+2m], u[l0+2m+1])
    #pragma unroll
    for (int m = 0; m < 8; ++m) {
        half2_t av = __builtin_bit_cast(half2_t, A[m]);
        float ue = (float)av.x;
        float uo = (float)av.y;
        yb[(size_t)(2 * m) * HH]     = acc[2 * m] + ce * ue;
        yb[(size_t)(2 * m + 1) * HH] = acc[2 * m + 1] + dv * uo;
    }
}

// ---------------------------------------------------------------------------
extern "C" void kernel_launch(void* const* d_in, const int* in_sizes, int n_in,
                              void* d_out, int out_size, void* d_ws, size_t ws_size,
                              hipStream_t stream) {
    const float* x   = (const float*)d_in[0];
    const float* lnw = (const float*)d_in[1];
    const float* lnb = (const float*)d_in[2];
    const float* LR  = (const float*)d_in[3];
    const float* LI  = (const float*)d_in[4];
    const float* Cr  = (const float*)d_in[5];
    const float* Ci  = (const float*)d_in[6];
    const float* Dp  = (const float*)d_in[7];
    float* y  = (float*)d_out;

    float2* Cpk = (float2*)d_ws;                      // NN*HH float2   (2 MB)
    float2* PQ  = Cpk + (size_t)NN * HH;              // NN*256 float2  (1 MB)
    float*  KT  = (float*)(PQ + (size_t)NN * 256);    // TT*HH          (512 KB)
    uint2*  KQ  = (uint2*)(KT + (size_t)TT * HH);     // NS*HH uint2    (512 KB)
    u32*    u2  = (u32*)(KQ + (size_t)NS * HH);       // BB*(LL/2)*HH + 16-row pad

    prep_kernel<<<LN_BLKS + 64 + 512, 256, 0, stream>>>(x, lnw, lnb, Cr, Ci,
                                                        LR, LI, u2, Cpk, PQ);
    build_kt<<<256, 256, 0, stream>>>(Cpk, PQ, KT);
    pack_k<<<NS * HH / 256, 256, 0, stream>>>(KT, KQ);
    conv_kernel<<<BB * (LL / (4 * LT)) * 8, 256, 0, stream>>>(u2, KQ, KT, Dp, y);
}

// Round 6
// 279.083 us; speedup vs baseline: 1.0026x; 1.0026x over previous
//
#include <hip/hip_runtime.h>
#include <math.h>

#define BB 8
#define LL 4096
#define HH 512
#define NN 512
#define TT 192        // truncated FIR length (R1 TT=512 / R2 TT=256 both absmax 0.5 => truncation @256 ~0)
#define NS 96         // tap-pair steps (TT/2)
#define LT 16         // output rows per wave tile

typedef _Float16 half2_t __attribute__((ext_vector_type(2)));
typedef unsigned int u32;
typedef unsigned short u16;

#if __has_builtin(__builtin_amdgcn_fdot2)
__device__ __forceinline__ float fdot2(half2_t a, half2_t b, float c) {
    return __builtin_amdgcn_fdot2(a, b, c, false);
}
#else
__device__ __forceinline__ float fdot2(half2_t a, half2_t b, float c) {
    return c + (float)a.x * (float)b.x + (float)a.y * (float)b.y;
}
#endif

// ---------------------------------------------------------------------------
// Kernel 1 (fused prep), 3 branches by blockIdx:
//   [0, 4096)     : LayerNorm + fp16 pack of adjacent L-row pairs
//   [4096, 4160)  : transpose+pack C [H,N] -> Cpk[N,H] float2(cr,ci)  (one LDS tile)
//   [4160, 4672)  : PQ[n][t] = float2(Re(s_n w_n^t), Im(s_n w_n^t)), one n per block
#define LN_BLKS (BB * LL / 8)
__global__ __launch_bounds__(256) void prep_kernel(const float* __restrict__ x,
                                                   const float* __restrict__ w,
                                                   const float* __restrict__ bia,
                                                   const float* __restrict__ Cr,
                                                   const float* __restrict__ Ci,
                                                   const float* __restrict__ LR,
                                                   const float* __restrict__ LI,
                                                   u32* __restrict__ u2,
                                                   float2* __restrict__ Cpk,
                                                   float2* __restrict__ PQ) {
    __shared__ float tile[64][65];
    if (blockIdx.x >= LN_BLKS + 64) {
        // ---- PQ branch: one n per block, t = tid (192 of 256 active) ----
        int n = blockIdx.x - (LN_BLKS + 64);
        int t = threadIdx.x;
        if (t < TT) {
            float lr = -expf(LR[n]);
            float li = expf(LI[n]);
            float el = expf(lr);
            float sn, cs;
            sincosf(li, &sn, &cs);
            float nr = el * cs - 1.0f;
            float ni = el * sn;
            float inv = 1.0f / (lr * lr + li * li);
            float sr = (nr * lr + ni * li) * inv;   // s = (e^lam-1)/lam
            float si = (ni * lr - nr * li) * inv;
            float tf = (float)t;
            float e2 = expf(lr * tf);
            float s2, c2;
            sincosf(li * tf, &s2, &c2);
            float er = e2 * c2, ei = e2 * s2;       // w^t
            PQ[(size_t)n * TT + t] = make_float2(sr * er - si * ei, sr * ei + si * er);
        }
        return;
    }
    if (blockIdx.x >= LN_BLKS) {
        // ---- transpose+pack branch: single tile, R then I ----
        int tb = blockIdx.x - LN_BLKS;   // 0..63
        int h0 = (tb & 7) * 64;
        int n0 = (tb >> 3) * 64;
        int c = threadIdx.x & 63;
        int r0 = threadIdx.x >> 6;
        float vr[16], vi[16];
        #pragma unroll
        for (int i = 0; i < 16; ++i) {
            int r = r0 + i * 4;
            tile[r][c] = Cr[(size_t)(h0 + r) * NN + n0 + c];
        }
        __syncthreads();
        #pragma unroll
        for (int i = 0; i < 16; ++i) vr[i] = tile[c][r0 + i * 4];
        __syncthreads();
        #pragma unroll
        for (int i = 0; i < 16; ++i) {
            int r = r0 + i * 4;
            tile[r][c] = Ci[(size_t)(h0 + r) * NN + n0 + c];
        }
        __syncthreads();
        #pragma unroll
        for (int i = 0; i < 16; ++i) vi[i] = tile[c][r0 + i * 4];
        #pragma unroll
        for (int i = 0; i < 16; ++i) {
            int r = r0 + i * 4;
            Cpk[(size_t)(n0 + r) * HH + h0 + c] = make_float2(vr[i], vi[i]);
        }
        return;
    }
    // ---- layernorm branch: one wave per L-row pair ----
    int wave = threadIdx.x >> 6;
    int lane = threadIdx.x & 63;
    size_t pair = (size_t)blockIdx.x * 4 + wave;
    const float* xr0 = x + pair * 2 * HH;
    const float* xr1 = xr0 + HH;
    float4 a0 = *(const float4*)(xr0 + lane * 4);
    float4 a1 = *(const float4*)(xr0 + 256 + lane * 4);
    float4 b0 = *(const float4*)(xr1 + lane * 4);
    float4 b1 = *(const float4*)(xr1 + 256 + lane * 4);
    float sA  = a0.x + a0.y + a0.z + a0.w + a1.x + a1.y + a1.z + a1.w;
    float qA  = a0.x*a0.x + a0.y*a0.y + a0.z*a0.z + a0.w*a0.w
              + a1.x*a1.x + a1.y*a1.y + a1.z*a1.z + a1.w*a1.w;
    float sB  = b0.x + b0.y + b0.z + b0.w + b1.x + b1.y + b1.z + b1.w;
    float qB  = b0.x*b0.x + b0.y*b0.y + b0.z*b0.z + b0.w*b0.w
              + b1.x*b1.x + b1.y*b1.y + b1.z*b1.z + b1.w*b1.w;
    #pragma unroll
    for (int off = 1; off < 64; off <<= 1) {
        sA += __shfl_xor(sA, off, 64);
        qA += __shfl_xor(qA, off, 64);
        sB += __shfl_xor(sB, off, 64);
        qB += __shfl_xor(qB, off, 64);
    }
    float mA = sA * (1.0f / 512.0f);
    float rA = rsqrtf(qA * (1.0f / 512.0f) - mA * mA + 1e-5f);
    float mB = sB * (1.0f / 512.0f);
    float rB = rsqrtf(qB * (1.0f / 512.0f) - mB * mB + 1e-5f);
    float4 w0 = *(const float4*)(w + lane * 4);
    float4 w1 = *(const float4*)(w + 256 + lane * 4);
    float4 c0 = *(const float4*)(bia + lane * 4);
    float4 c1 = *(const float4*)(bia + 256 + lane * 4);
    uint4 o0, o1;
    {
        half2_t p;
        p.x = (_Float16)((a0.x - mA) * rA * w0.x + c0.x);
        p.y = (_Float16)((b0.x - mB) * rB * w0.x + c0.x);
        o0.x = __builtin_bit_cast(u32, p);
        p.x = (_Float16)((a0.y - mA) * rA * w0.y + c0.y);
        p.y = (_Float16)((b0.y - mB) * rB * w0.y + c0.y);
        o0.y = __builtin_bit_cast(u32, p);
        p.x = (_Float16)((a0.z - mA) * rA * w0.z + c0.z);
        p.y = (_Float16)((b0.z - mB) * rB * w0.z + c0.z);
        o0.z = __builtin_bit_cast(u32, p);
        p.x = (_Float16)((a0.w - mA) * rA * w0.w + c0.w);
        p.y = (_Float16)((b0.w - mB) * rB * w0.w + c0.w);
        o0.w = __builtin_bit_cast(u32, p);
        p.x = (_Float16)((a1.x - mA) * rA * w1.x + c1.x);
        p.y = (_Float16)((b1.x - mB) * rB * w1.x + c1.x);
        o1.x = __builtin_bit_cast(u32, p);
        p.x = (_Float16)((a1.y - mA) * rA * w1.y + c1.y);
        p.y = (_Float16)((b1.y - mB) * rB * w1.y + c1.y);
        o1.y = __builtin_bit_cast(u32, p);
        p.x = (_Float16)((a1.z - mA) * rA * w1.z + c1.z);
        p.y = (_Float16)((b1.z - mB) * rB * w1.z + c1.z);
        o1.z = __builtin_bit_cast(u32, p);
        p.x = (_Float16)((a1.w - mA) * rA * w1.w + c1.w);
        p.y = (_Float16)((b1.w - mB) * rB * w1.w + c1.w);
        o1.w = __builtin_bit_cast(u32, p);
    }
    *(uint4*)(u2 + pair * HH + lane * 4) = o0;
    *(uint4*)(u2 + pair * HH + 256 + lane * 4) = o1;
}

// ---------------------------------------------------------------------------
// Kernel 2: KT[t][h] (fp32, for K[0]) AND the fp16 conv pairs KQ, directly.
// KQ[s][h] = uint2{ kx = (lo K[191-2s], hi K[190-2s]),
//                   ky = (lo K[192-2s] (0 @s=0), hi K[191-2s]) }
// Block computes t0 = 2*(blk>>1), t0+1 for one h-half.  k0=K[t0] (even),
// k1=K[t0+1] (odd).  sa = (190-t0)/2:  kx(sa) = (k1,k0) [u32 write],
// ky.hi(sa) = k1, ky.lo(sa+1) = k0; t0==190 also zeroes ky.lo(0).
__global__ __launch_bounds__(256) void build_kt(const float2* __restrict__ Cpk,
                                                const float2* __restrict__ PQ,
                                                float* __restrict__ KT,
                                                uint2* __restrict__ KQ) {
    int blk = blockIdx.x;            // 192 blocks
    int t0 = (blk >> 1) * 2;
    int half = blk & 1;
    int h = half * 256 + threadIdx.x;
    float k0 = 0.0f, k1 = 0.0f;
    const float4* pq4 = (const float4*)PQ;   // (P[t0],Q[t0],P[t0+1],Q[t0+1]) at n*96+t0/2
    int pqoff = t0 >> 1;
    #pragma unroll 8
    for (int n = 0; n < NN; ++n) {
        float2 c = Cpk[(size_t)n * HH + h];
        float4 f = pq4[(size_t)n * (TT / 2) + pqoff];
        k0 = fmaf(c.x, f.x, k0);
        k0 = fmaf(-c.y, f.y, k0);
        k1 = fmaf(c.x, f.z, k1);
        k1 = fmaf(-c.y, f.w, k1);
    }
    KT[(size_t)t0 * HH + h] = k0;
    KT[(size_t)(t0 + 1) * HH + h] = k1;
    // fused fp16 pack
    int sa = (190 - t0) >> 1;        // 0..95
    half2_t kx;
    kx.x = (_Float16)k1;
    kx.y = (_Float16)k0;
    u16 h0b = __builtin_bit_cast(u16, (_Float16)k0);
    u16 h1b = __builtin_bit_cast(u16, (_Float16)k1);
    u32* KQ32 = (u32*)KQ;
    u16* KQ16 = (u16*)KQ;
    KQ32[(size_t)sa * 1024 + h * 2] = __builtin_bit_cast(u32, kx);          // kx(sa)
    KQ16[((size_t)sa * 1024 + h * 2 + 1) * 2 + 1] = h1b;                    // ky.hi(sa)
    if (sa + 1 < NS)
        KQ16[((size_t)(sa + 1) * 1024 + h * 2 + 1) * 2 + 0] = h0b;          // ky.lo(sa+1)
    if (t0 == 190)
        KQ16[((size_t)0 * 1024 + h * 2 + 1) * 2 + 0] = 0;                   // ky.lo(0)=K[192]=0
}

// ---------------------------------------------------------------------------
// Kernel 3: causal FIR conv via v_dot2_f32_f16 + D*u residual.
// Block = 64 h x 4 consecutive l-tiles (wave = tile, lane = h).
// odd  j=2m+1: acc += dot2(v[Vm1+s+m+1], kx[s]),  s=0..NS-1
// even j=2m  : acc += dot2(v[Vm1+s+m],   ky[s]),  s=0..NS-1  (+ K[0]*u[l0+j])
// K ring = 8 (refill 8 steps ahead), u ring = 2x16 (32 steps ahead).
// u2 padded by 16 rows (prefetch overruns past end by <=8 entries).

template <bool PRED>
__device__ __forceinline__ u32 load_v(const u32* __restrict__ ub2, int vi) {
    int c = vi;
    if (PRED && c < 0) c = 0;
    u32 val = ub2[(size_t)c * HH];
    if (PRED && vi < 0) val = 0u;
    return val;
}

#define SLOT(p) ((p) < 16 ? W[(p)] : X[(p) - 16])

// KMODE: 1 = load 16 taps (knext+k), 2 = load first 8 only (tail block)
template <bool PRED, bool LOADU, int KMODE>
__device__ __forceinline__ void conv_block(const u32* __restrict__ ub2,
                                           const uint2* __restrict__ kqb,
                                           float (&acc)[LT], u32 (&W)[16], u32 (&X)[16],
                                           uint2 (&KR)[8], int ubase, int knext) {
    #pragma unroll
    for (int k = 0; k < 16; ++k) {
        const bool dok = (KMODE == 1) || (KMODE == 2 && k < 8);
        u32 nv = 0u;
        uint2 kv = make_uint2(0u, 0u);
        if (LOADU) nv = load_v<PRED>(ub2, ubase + k);
        if (dok) kv = kqb[(size_t)(knext + k) * HH];
        uint2 kq = KR[k & 7];
        half2_t kx = __builtin_bit_cast(half2_t, kq.x);
        half2_t ky = __builtin_bit_cast(half2_t, kq.y);
        #pragma unroll
        for (int m = 0; m < 8; ++m) {
            half2_t ve = __builtin_bit_cast(half2_t, SLOT(k + m));
            half2_t vo = __builtin_bit_cast(half2_t, SLOT(k + m + 1));
            acc[2 * m]     = fdot2(ve, ky, acc[2 * m]);
            acc[2 * m + 1] = fdot2(vo, kx, acc[2 * m + 1]);
        }
        if (LOADU) W[k] = nv;
        if (dok) KR[k & 7] = kv;
    }
}

template <bool PRED>
__device__ __forceinline__ void conv_all(const u32* __restrict__ ub2,
                                         const uint2* __restrict__ kqb,
                                         float (&acc)[LT], u32 (&A)[16], u32 (&B)[16],
                                         uint2 (&KR)[8], int Vm1) {
    #pragma unroll
    for (int j = 0; j < 16; ++j) A[j] = load_v<PRED>(ub2, Vm1 + j);
    #pragma unroll
    for (int j = 0; j < 16; ++j) B[j] = load_v<PRED>(ub2, Vm1 + 16 + j);
    #pragma unroll
    for (int q = 0; q < 8; ++q) KR[q] = kqb[(size_t)q * HH];
    #pragma unroll 1
    for (int sbp = 0; sbp < 2; ++sbp) {   // sb = 0..3; knext(sb) = 16*sb+8
        conv_block<PRED, true, 1>(ub2, kqb, acc, A, B, KR,
                                  Vm1 + 32 * sbp + 32, 32 * sbp + 8);
        conv_block<PRED, true, 1>(ub2, kqb, acc, B, A, KR,
                                  Vm1 + 32 * sbp + 48, 32 * sbp + 24);
    }
    // sb = 4: u loads cover v[l0/2..l0/2+15] into A; K loads s=72..87
    conv_block<PRED, true, 1>(ub2, kqb, acc, A, B, KR, Vm1 + 96, 72);
    // sb = 5: K loads s=88..95 at k<8; no u loads; A preserved for epilogue
    conv_block<PRED, false, 2>(ub2, kqb, acc, B, A, KR, 0, 88);
}

__global__ __launch_bounds__(256, 4) void conv_kernel(const u32* __restrict__ u2,
                                                      const uint2* __restrict__ KQ,
                                                      const float* __restrict__ KT,
                                                      const float* __restrict__ Dp,
                                                      float* __restrict__ y) {
    int lane = threadIdx.x & 63;
    int g = threadIdx.x >> 6;            // wave = l-subtile
    int blk = blockIdx.x;
    int hg = blk & 7;                    // 8 h-groups of 64
    int tg = (blk >> 3) & 63;            // 64 tile-groups of 4 tiles
    int b = blk >> 9;                    // 8 batches
    int h = hg * 64 + lane;
    int l0 = (tg * 4 + g) * LT;
    const u32* ub2 = u2 + (size_t)b * (LL / 2) * HH + h;
    const uint2* kqb = KQ + h;
    int Vm1 = l0 / 2 - NS;
    float acc[LT];
    u32 A[16], B[16];
    uint2 KR[8];
    #pragma unroll
    for (int j = 0; j < LT; ++j) acc[j] = 0.0f;
    if (l0 >= TT) {
        conv_all<false>(ub2, kqb, acc, A, B, KR, Vm1);
    } else {
        conv_all<true>(ub2, kqb, acc, A, B, KR, Vm1);
    }
    float dv = Dp[h];
    float k0f = KT[h];          // K[0]
    float ce = k0f + dv;
    float* yb = y + ((size_t)b * LL + l0) * HH + h;
    // A[m] = v[l0/2+m] = (u[l0+2m], u[l0+2m+1])
    #pragma unroll
    for (int m = 0; m < 8; ++m) {
        half2_t av = __builtin_bit_cast(half2_t, A[m]);
        float ue = (float)av.x;
        float uo = (float)av.y;
        yb[(size_t)(2 * m) * HH]     = acc[2 * m] + ce * ue;
        yb[(size_t)(2 * m + 1) * HH] = acc[2 * m + 1] + dv * uo;
    }
}

// ---------------------------------------------------------------------------
extern "C" void kernel_launch(void* const* d_in, const int* in_sizes, int n_in,
                              void* d_out, int out_size, void* d_ws, size_t ws_size,
                              hipStream_t stream) {
    const float* x   = (const float*)d_in[0];
    const float* lnw = (const float*)d_in[1];
    const float* lnb = (const float*)d_in[2];
    const float* LR  = (const float*)d_in[3];
    const float* LI  = (const float*)d_in[4];
    const float* Cr  = (const float*)d_in[5];
    const float* Ci  = (const float*)d_in[6];
    const float* Dp  = (const float*)d_in[7];
    float* y  = (float*)d_out;

    float2* Cpk = (float2*)d_ws;                      // NN*HH float2   (2 MB)
    float2* PQ  = Cpk + (size_t)NN * HH;              // NN*TT float2   (0.75 MB)
    float*  KT  = (float*)(PQ + (size_t)NN * TT);     // TT*HH          (384 KB)
    uint2*  KQ  = (uint2*)(KT + (size_t)TT * HH);     // NS*HH uint2    (384 KB)
    u32*    u2  = (u32*)(KQ + (size_t)NS * HH);       // BB*(LL/2)*HH + 16-row pad

    prep_kernel<<<LN_BLKS + 64 + NN, 256, 0, stream>>>(x, lnw, lnb, Cr, Ci,
                                                       LR, LI, u2, Cpk, PQ);
    build_kt<<<TT, 256, 0, stream>>>(Cpk, PQ, KT, KQ);
    conv_kernel<<<BB * (LL / (4 * LT)) * 8, 256, 0, stream>>>(u2, KQ, KT, Dp, y);
}

// Round 7
// 252.458 us; speedup vs baseline: 1.1084x; 1.1055x over previous
//
#include <hip/hip_runtime.h>
#include <math.h>

#define BB 8
#define LL 4096
#define HH 512
#define NN 512
#define TT 192        // truncated FIR length
#define NS 96         // tap-pair steps (TT/2)
#define LT 16         // output rows per wave tile

typedef _Float16 half2_t __attribute__((ext_vector_type(2)));
typedef unsigned int u32;
typedef unsigned short u16;

#if __has_builtin(__builtin_amdgcn_fdot2)
__device__ __forceinline__ float fdot2(half2_t a, half2_t b, float c) {
    return __builtin_amdgcn_fdot2(a, b, c, false);
}
#else
__device__ __forceinline__ float fdot2(half2_t a, half2_t b, float c) {
    return c + (float)a.x * (float)b.x + (float)a.y * (float)b.y;
}
#endif

// ---------------------------------------------------------------------------
// Kernel 1 (fused prep), 3 branches by blockIdx:
//   [0, 4096)     : LayerNorm + fp16 pack of adjacent L-row pairs
//   [4096, 4160)  : transpose+pack C [H,N] -> Cpk[N,H] float2(cr,ci)
//   [4160, 4672)  : PQ[n][t] = float2(Re(s_n w_n^t), Im(s_n w_n^t))
#define LN_BLKS (BB * LL / 8)
__global__ __launch_bounds__(256) void prep_kernel(const float* __restrict__ x,
                                                   const float* __restrict__ w,
                                                   const float* __restrict__ bia,
                                                   const float* __restrict__ Cr,
                                                   const float* __restrict__ Ci,
                                                   const float* __restrict__ LR,
                                                   const float* __restrict__ LI,
                                                   u32* __restrict__ u2,
                                                   float2* __restrict__ Cpk,
                                                   float2* __restrict__ PQ) {
    __shared__ float tile[64][65];
    if (blockIdx.x >= LN_BLKS + 64) {
        // ---- PQ branch: one n per block, t = tid (192 of 256 active) ----
        int n = blockIdx.x - (LN_BLKS + 64);
        int t = threadIdx.x;
        if (t < TT) {
            float lr = -expf(LR[n]);
            float li = expf(LI[n]);
            float el = expf(lr);
            float sn, cs;
            sincosf(li, &sn, &cs);
            float nr = el * cs - 1.0f;
            float ni = el * sn;
            float inv = 1.0f / (lr * lr + li * li);
            float sr = (nr * lr + ni * li) * inv;   // s = (e^lam-1)/lam
            float si = (ni * lr - nr * li) * inv;
            float tf = (float)t;
            float e2 = expf(lr * tf);
            float s2, c2;
            sincosf(li * tf, &s2, &c2);
            float er = e2 * c2, ei = e2 * s2;       // w^t
            PQ[(size_t)n * TT + t] = make_float2(sr * er - si * ei, sr * ei + si * er);
        }
        return;
    }
    if (blockIdx.x >= LN_BLKS) {
        // ---- transpose+pack branch: single tile, R then I ----
        int tb = blockIdx.x - LN_BLKS;   // 0..63
        int h0 = (tb & 7) * 64;
        int n0 = (tb >> 3) * 64;
        int c = threadIdx.x & 63;
        int r0 = threadIdx.x >> 6;
        float vr[16], vi[16];
        #pragma unroll
        for (int i = 0; i < 16; ++i) {
            int r = r0 + i * 4;
            tile[r][c] = Cr[(size_t)(h0 + r) * NN + n0 + c];
        }
        __syncthreads();
        #pragma unroll
        for (int i = 0; i < 16; ++i) vr[i] = tile[c][r0 + i * 4];
        __syncthreads();
        #pragma unroll
        for (int i = 0; i < 16; ++i) {
            int r = r0 + i * 4;
            tile[r][c] = Ci[(size_t)(h0 + r) * NN + n0 + c];
        }
        __syncthreads();
        #pragma unroll
        for (int i = 0; i < 16; ++i) vi[i] = tile[c][r0 + i * 4];
        #pragma unroll
        for (int i = 0; i < 16; ++i) {
            int r = r0 + i * 4;
            Cpk[(size_t)(n0 + r) * HH + h0 + c] = make_float2(vr[i], vi[i]);
        }
        return;
    }
    // ---- layernorm branch: one wave per L-row pair ----
    int wave = threadIdx.x >> 6;
    int lane = threadIdx.x & 63;
    size_t pair = (size_t)blockIdx.x * 4 + wave;
    const float* xr0 = x + pair * 2 * HH;
    const float* xr1 = xr0 + HH;
    float4 a0 = *(const float4*)(xr0 + lane * 4);
    float4 a1 = *(const float4*)(xr0 + 256 + lane * 4);
    float4 b0 = *(const float4*)(xr1 + lane * 4);
    float4 b1 = *(const float4*)(xr1 + 256 + lane * 4);
    float sA  = a0.x + a0.y + a0.z + a0.w + a1.x + a1.y + a1.z + a1.w;
    float qA  = a0.x*a0.x + a0.y*a0.y + a0.z*a0.z + a0.w*a0.w
              + a1.x*a1.x + a1.y*a1.y + a1.z*a1.z + a1.w*a1.w;
    float sB  = b0.x + b0.y + b0.z + b0.w + b1.x + b1.y + b1.z + b1.w;
    float qB  = b0.x*b0.x + b0.y*b0.y + b0.z*b0.z + b0.w*b0.w
              + b1.x*b1.x + b1.y*b1.y + b1.z*b1.z + b1.w*b1.w;
    #pragma unroll
    for (int off = 1; off < 64; off <<= 1) {
        sA += __shfl_xor(sA, off, 64);
        qA += __shfl_xor(qA, off, 64);
        sB += __shfl_xor(sB, off, 64);
        qB += __shfl_xor(qB, off, 64);
    }
    float mA = sA * (1.0f / 512.0f);
    float rA = rsqrtf(qA * (1.0f / 512.0f) - mA * mA + 1e-5f);
    float mB = sB * (1.0f / 512.0f);
    float rB = rsqrtf(qB * (1.0f / 512.0f) - mB * mB + 1e-5f);
    float4 w0 = *(const float4*)(w + lane * 4);
    float4 w1 = *(const float4*)(w + 256 + lane * 4);
    float4 c0 = *(const float4*)(bia + lane * 4);
    float4 c1 = *(const float4*)(bia + 256 + lane * 4);
    uint4 o0, o1;
    {
        half2_t p;
        p.x = (_Float16)((a0.x - mA) * rA * w0.x + c0.x);
        p.y = (_Float16)((b0.x - mB) * rB * w0.x + c0.x);
        o0.x = __builtin_bit_cast(u32, p);
        p.x = (_Float16)((a0.y - mA) * rA * w0.y + c0.y);
        p.y = (_Float16)((b0.y - mB) * rB * w0.y + c0.y);
        o0.y = __builtin_bit_cast(u32, p);
        p.x = (_Float16)((a0.z - mA) * rA * w0.z + c0.z);
        p.y = (_Float16)((b0.z - mB) * rB * w0.z + c0.z);
        o0.z = __builtin_bit_cast(u32, p);
        p.x = (_Float16)((a0.w - mA) * rA * w0.w + c0.w);
        p.y = (_Float16)((b0.w - mB) * rB * w0.w + c0.w);
        o0.w = __builtin_bit_cast(u32, p);
        p.x = (_Float16)((a1.x - mA) * rA * w1.x + c1.x);
        p.y = (_Float16)((b1.x - mB) * rB * w1.x + c1.x);
        o1.x = __builtin_bit_cast(u32, p);
        p.x = (_Float16)((a1.y - mA) * rA * w1.y + c1.y);
        p.y = (_Float16)((b1.y - mB) * rB * w1.y + c1.y);
        o1.y = __builtin_bit_cast(u32, p);
        p.x = (_Float16)((a1.z - mA) * rA * w1.z + c1.z);
        p.y = (_Float16)((b1.z - mB) * rB * w1.z + c1.z);
        o1.z = __builtin_bit_cast(u32, p);
        p.x = (_Float16)((a1.w - mA) * rA * w1.w + c1.w);
        p.y = (_Float16)((b1.w - mB) * rB * w1.w + c1.w);
        o1.w = __builtin_bit_cast(u32, p);
    }
    *(uint4*)(u2 + pair * HH + lane * 4) = o0;
    *(uint4*)(u2 + pair * HH + 256 + lane * 4) = o1;
}

// ---------------------------------------------------------------------------
// Kernel 2: KT[t][h] = sum_n cr*P[n][t] - ci*Q[n][t].  2 t's per block,
// h-half per block (192 blocks); PQ loads wave-uniform, Cpk coalesced float2.
__global__ __launch_bounds__(256) void build_kt(const float2* __restrict__ Cpk,
                                                const float2* __restrict__ PQ,
                                                float* __restrict__ KT) {
    int blk = blockIdx.x;
    int t0 = (blk >> 1) * 2;
    int half = blk & 1;
    int h = half * 256 + threadIdx.x;
    float k0 = 0.0f, k1 = 0.0f;
    const float4* pq4 = (const float4*)PQ;
    int pqoff = t0 >> 1;
    #pragma unroll 8
    for (int n = 0; n < NN; ++n) {
        float2 c = Cpk[(size_t)n * HH + h];
        float4 f = pq4[(size_t)n * (TT / 2) + pqoff];   // (P[t0],Q[t0],P[t0+1],Q[t0+1])
        k0 = fmaf(c.x, f.x, k0);
        k0 = fmaf(-c.y, f.y, k0);
        k1 = fmaf(c.x, f.z, k1);
        k1 = fmaf(-c.y, f.w, k1);
    }
    KT[(size_t)t0 * HH + h] = k0;
    KT[(size_t)(t0 + 1) * HH + h] = k1;
}

// ---------------------------------------------------------------------------
// Kernel 3: pack K into step-indexed swapped half2 pairs (coalesced writes).
// KQ[s][h].x = kx = (lo K[191-2s], hi K[190-2s])   (odd-j pair)
// KQ[s][h].y = ky = (lo K[192-2s] (0 @s=0), hi K[191-2s])  (even-j pair)
__global__ void pack_k(const float* __restrict__ KT, uint2* __restrict__ KQ) {
    int idx = blockIdx.x * 256 + threadIdx.x;   // NS*HH entries
    int s = idx >> 9;
    int h = idx & 511;
    float k0 = KT[(190 - 2 * s) * HH + h];
    float k1 = KT[(191 - 2 * s) * HH + h];
    float k2 = (s == 0) ? 0.0f : KT[(192 - 2 * s) * HH + h];
    half2_t kx, ky;
    kx.x = (_Float16)k1; kx.y = (_Float16)k0;
    ky.x = (_Float16)k2; ky.y = (_Float16)k1;
    KQ[idx] = make_uint2(__builtin_bit_cast(u32, kx), __builtin_bit_cast(u32, ky));
}

// ---------------------------------------------------------------------------
// Kernel 4: causal FIR conv via v_dot2_f32_f16 + D*u residual.
// Block = 64 h x 4 l-tile waves.  All taps for the block's 64-h slice staged
// in LDS once (48 KB): tap reads are ds_read_b64 with compile-time offsets,
// no K registers, no K ring -> live state ~60 VGPR, no spill.
// u: 2x16 register ring, prefetched 32 steps ahead.  u2 padded 16 rows.

template <bool PRED>
__device__ __forceinline__ u32 load_v(const u32* __restrict__ ub2, int vi) {
    int c = vi;
    if (PRED && c < 0) c = 0;
    u32 val = ub2[(size_t)c * HH];
    if (PRED && vi < 0) val = 0u;
    return val;
}

#define SLOT(p) ((p) < 16 ? W[(p)] : X[(p) - 16])

// One 16-step block; W holds v[R..R+15], X v[R+16..R+31], R = Vm1+16*sb.
// Step k: taps from LDS at (soff+k), consumes SLOT(k+m)/(k+m+1);
// if LOADU, loads v[ubase+k] into dead slot W[k].
template <bool PRED, bool LOADU>
__device__ __forceinline__ void conv_block(const u32* __restrict__ ub2,
                                           const uint2* klds,
                                           float (&acc)[LT], u32 (&W)[16], u32 (&X)[16],
                                           int ubase, int soff) {
    #pragma unroll
    for (int k = 0; k < 16; ++k) {
        u32 nv = 0u;
        if (LOADU) nv = load_v<PRED>(ub2, ubase + k);
        uint2 kq = klds[(soff + k) * 64];
        half2_t kx = __builtin_bit_cast(half2_t, kq.x);
        half2_t ky = __builtin_bit_cast(half2_t, kq.y);
        #pragma unroll
        for (int m = 0; m < 8; ++m) {
            half2_t ve = __builtin_bit_cast(half2_t, SLOT(k + m));
            half2_t vo = __builtin_bit_cast(half2_t, SLOT(k + m + 1));
            acc[2 * m]     = fdot2(ve, ky, acc[2 * m]);
            acc[2 * m + 1] = fdot2(vo, kx, acc[2 * m + 1]);
        }
        if (LOADU) W[k] = nv;
    }
}

template <bool PRED>
__device__ __forceinline__ void conv_all(const u32* __restrict__ ub2,
                                         const uint2* klds,
                                         float (&acc)[LT], u32 (&A)[16], u32 (&B)[16],
                                         int Vm1) {
    #pragma unroll
    for (int j = 0; j < 16; ++j) A[j] = load_v<PRED>(ub2, Vm1 + j);
    #pragma unroll
    for (int j = 0; j < 16; ++j) B[j] = load_v<PRED>(ub2, Vm1 + 16 + j);
    #pragma unroll 1
    for (int sbp = 0; sbp < 2; ++sbp) {   // sb = 0..3
        conv_block<PRED, true>(ub2, klds, acc, A, B, Vm1 + 32 + 32 * sbp, 32 * sbp);
        conv_block<PRED, true>(ub2, klds, acc, B, A, Vm1 + 48 + 32 * sbp, 32 * sbp + 16);
    }
    // sb = 4: loads v[Vm1+96..111] = v[l0/2..l0/2+15] into A (epilogue data)
    conv_block<PRED, true>(ub2, klds, acc, A, B, Vm1 + 96, 64);
    // sb = 5: no loads; A preserved
    conv_block<PRED, false>(ub2, klds, acc, B, A, 0, 80);
}

__global__ __launch_bounds__(256) void conv_kernel(const u32* __restrict__ u2,
                                                   const uint2* __restrict__ KQ,
                                                   const float* __restrict__ KT,
                                                   const float* __restrict__ Dp,
                                                   float* __restrict__ y) {
    __shared__ uint2 KL[NS * 64];        // 48 KB: taps for this block's 64 h's
    int tid = threadIdx.x;
    int lane = tid & 63;
    int g = tid >> 6;                    // wave = l-subtile
    int blk = blockIdx.x;
    int hg = blk & 7;                    // 8 h-groups of 64
    int tg = (blk >> 3) & 63;            // 64 tile-groups of 4 tiles
    int b = blk >> 9;                    // 8 batches
    int h = hg * 64 + lane;
    int l0 = (tg * 4 + g) * LT;
    // cooperative K stage: NS*64 uint2 = 3072 uint4
    {
        const uint2* kg = KQ + hg * 64;
        #pragma unroll
        for (int it = 0; it < (NS * 64 / 2) / 256; ++it) {
            int i = it * 256 + tid;      // uint4 index
            int s = i >> 5;
            int q = i & 31;
            uint4 v = *(const uint4*)(kg + (size_t)s * HH + q * 2);
            *(uint4*)(&KL[s * 64 + q * 2]) = v;
        }
    }
    __syncthreads();
    const u32* ub2 = u2 + (size_t)b * (LL / 2) * HH + h;
    const uint2* klds = &KL[lane];
    int Vm1 = l0 / 2 - NS;
    float acc[LT];
    u32 A[16], B[16];
    #pragma unroll
    for (int j = 0; j < LT; ++j) acc[j] = 0.0f;
    if (l0 >= TT) {
        conv_all<false>(ub2, klds, acc, A, B, Vm1);
    } else {
        conv_all<true>(ub2, klds, acc, A, B, Vm1);
    }
    float dv = Dp[h];
    float k0f = KT[h];          // K[0]
    float ce = k0f + dv;
    float* yb = y + ((size_t)b * LL + l0) * HH + h;
    // A[m] = v[l0/2+m] = (u[l0+2m], u[l0+2m+1])
    #pragma unroll
    for (int m = 0; m < 8; ++m) {
        half2_t av = __builtin_bit_cast(half2_t, A[m]);
        float ue = (float)av.x;
        float uo = (float)av.y;
        yb[(size_t)(2 * m) * HH]     = acc[2 * m] + ce * ue;
        yb[(size_t)(2 * m + 1) * HH] = acc[2 * m + 1] + dv * uo;
    }
}

// ---------------------------------------------------------------------------
extern "C" void kernel_launch(void* const* d_in, const int* in_sizes, int n_in,
                              void* d_out, int out_size, void* d_ws, size_t ws_size,
                              hipStream_t stream) {
    const float* x   = (const float*)d_in[0];
    const float* lnw = (const float*)d_in[1];
    const float* lnb = (const float*)d_in[2];
    const float* LR  = (const float*)d_in[3];
    const float* LI  = (const float*)d_in[4];
    const float* Cr  = (const float*)d_in[5];
    const float* Ci  = (const float*)d_in[6];
    const float* Dp  = (const float*)d_in[7];
    float* y  = (float*)d_out;

    float2* Cpk = (float2*)d_ws;                      // NN*HH float2   (2 MB)
    float2* PQ  = Cpk + (size_t)NN * HH;              // NN*TT float2   (0.75 MB)
    float*  KT  = (float*)(PQ + (size_t)NN * TT);     // TT*HH          (384 KB)
    uint2*  KQ  = (uint2*)(KT + (size_t)TT * HH);     // NS*HH uint2    (384 KB)
    u32*    u2  = (u32*)(KQ + (size_t)NS * HH);       // BB*(LL/2)*HH + 16-row pad

    prep_kernel<<<LN_BLKS + 64 + NN, 256, 0, stream>>>(x, lnw, lnb, Cr, Ci,
                                                       LR, LI, u2, Cpk, PQ);
    build_kt<<<TT, 256, 0, stream>>>(Cpk, PQ, KT);
    pack_k<<<NS * HH / 256, 256, 0, stream>>>(KT, KQ);
    conv_kernel<<<BB * (LL / (4 * LT)) * 8, 256, 0, stream>>>(u2, KQ, KT, Dp, y);
}